// Round 2
// baseline (981.294 us; speedup 1.0000x reference)
//
#include <hip/hip_runtime.h>
#include <stdint.h>
#include <math.h>

#define T_TOK 2048
#define DIM   2048
#define FDIM  2048
#define NE    8

#define BM 128
#define BN 128
#define BK 32
#define LDB 40   // fallback path only
#define MATSZ 4194304ull  // 2048*2048

typedef unsigned short u16;
typedef short s16x8 __attribute__((ext_vector_type(8)));
typedef float f32x4 __attribute__((ext_vector_type(4)));

__device__ __forceinline__ u16 f2bf(float f) {
    union { float f; unsigned int u; } v; v.f = f;
    unsigned int r = v.u + 0x7FFFu + ((v.u >> 16) & 1u);  // RNE
    return (u16)(r >> 16);
}

// async 16B global -> LDS. lds ptr must be wave-uniform; HW scatters lane*16.
__device__ __forceinline__ void gload_lds16(const void* g, void* l) {
    __builtin_amdgcn_global_load_lds((const __attribute__((address_space(1))) void*)g,
                                     (__attribute__((address_space(3))) void*)l, 16, 0, 0);
}

// ---------------- router ----------------
__global__ __launch_bounds__(256) void router_k(
    const float* __restrict__ x, const float* __restrict__ rw,
    float* __restrict__ score, int* __restrict__ eidx, int* __restrict__ counts)
{
    int t = blockIdx.x;
    int tid = threadIdx.x;
    float p[8] = {0.f,0.f,0.f,0.f,0.f,0.f,0.f,0.f};
    const float* xrow = x + (size_t)t * DIM;
    for (int d = tid; d < DIM; d += 256) {
        float xv = xrow[d];
        const float4* r = (const float4*)(rw + (size_t)d * 8);
        float4 r0 = r[0], r1 = r[1];
        p[0] += xv * r0.x; p[1] += xv * r0.y; p[2] += xv * r0.z; p[3] += xv * r0.w;
        p[4] += xv * r1.x; p[5] += xv * r1.y; p[6] += xv * r1.z; p[7] += xv * r1.w;
    }
    #pragma unroll
    for (int off = 32; off > 0; off >>= 1) {
        #pragma unroll
        for (int e = 0; e < 8; ++e) p[e] += __shfl_down(p[e], off);
    }
    __shared__ float red[4][8];
    int wave = tid >> 6, lane = tid & 63;
    if (lane == 0) {
        #pragma unroll
        for (int e = 0; e < 8; ++e) red[wave][e] = p[e];
    }
    __syncthreads();
    if (tid == 0) {
        float lg[8];
        #pragma unroll
        for (int e = 0; e < 8; ++e) lg[e] = red[0][e] + red[1][e] + red[2][e] + red[3][e];
        int best = 0; float bv = lg[0];
        #pragma unroll
        for (int e = 1; e < 8; ++e) { if (lg[e] > bv) { bv = lg[e]; best = e; } }
        score[t] = 1.f / (1.f + expf(-bv));
        eidx[t] = best;
        atomicAdd(&counts[best], 1);
    }
}

__global__ void scan_k(const int* __restrict__ counts, int* __restrict__ offs,
                       int* __restrict__ fill)
{
    if (threadIdx.x == 0 && blockIdx.x == 0) {
        int run = 0;
        for (int e = 0; e < NE; ++e) { offs[e] = run; fill[e] = run; run += counts[e]; }
    }
}

// ---------------- gather ----------------
__global__ __launch_bounds__(256) void gather_k(
    const float* __restrict__ x, const float* __restrict__ score,
    const int* __restrict__ eidx, int* __restrict__ fill,
    int* __restrict__ tokmap, u16* __restrict__ xsc, u16* __restrict__ xbf)
{
    int t = blockIdx.x, tid = threadIdx.x;
    __shared__ int sp;
    if (tid == 0) {
        int e = eidx[t];
        int p = atomicAdd(&fill[e], 1);
        tokmap[p] = t;
        sp = p;
    }
    __syncthreads();
    int pos = sp;
    float s = score[t];
    const float4* xr = (const float4*)(x + (size_t)t * DIM);
    float4 a = xr[tid * 2], b = xr[tid * 2 + 1];
    alignas(16) u16 raw[8] = { f2bf(a.x), f2bf(a.y), f2bf(a.z), f2bf(a.w),
                               f2bf(b.x), f2bf(b.y), f2bf(b.z), f2bf(b.w) };
    alignas(16) u16 scl[8] = { f2bf(a.x*s), f2bf(a.y*s), f2bf(a.z*s), f2bf(a.w*s),
                               f2bf(b.x*s), f2bf(b.y*s), f2bf(b.z*s), f2bf(b.w*s) };
    *(s16x8*)(xbf + (size_t)t * DIM + tid * 8)   = *(s16x8*)raw;
    *(s16x8*)(xsc + (size_t)pos * DIM + tid * 8) = *(s16x8*)scl;
}

// ---------------- weight convert+transpose: fp32 [K][N] -> bf16 [N][K] ----------------
// matrix m: 0..7 gate, 8..15 up, 16..23 down, 24 sg, 25 su, 26 sd
__global__ __launch_bounds__(256) void wtrans_k(
    const float* __restrict__ gw, const float* __restrict__ uw,
    const float* __restrict__ dwn, const float* __restrict__ sgw,
    const float* __restrict__ suw, const float* __restrict__ sdw,
    u16* __restrict__ wt)
{
    int bid = blockIdx.x;
    int m = bid >> 5;
    int strip = bid & 31;
    const float* src;
    if      (m < 8)  src = gw  + (size_t)m * MATSZ;
    else if (m < 16) src = uw  + (size_t)(m - 8) * MATSZ;
    else if (m < 24) src = dwn + (size_t)(m - 16) * MATSZ;
    else if (m == 24) src = sgw;
    else if (m == 25) src = suw;
    else              src = sdw;
    u16* dst = wt + (size_t)m * MATSZ;

    int tid = threadIdx.x;
    int n = strip * 64 + (tid & 63);   // lane-consecutive n -> coalesced fp32 reads
    int w = tid >> 6;                  // wave owns a 512-wide k span
    const float* sp = src + n;
    u16* dp = dst + (size_t)n * 2048 + w * 512;

    #pragma unroll 2
    for (int c = 0; c < 64; ++c) {
        int k = w * 512 + c * 8;
        alignas(16) u16 t8[8];
        #pragma unroll
        for (int j = 0; j < 8; ++j) t8[j] = f2bf(sp[(size_t)(k + j) * 2048]);
        *(s16x8*)(dp + c * 8) = *(s16x8*)t8;   // per-lane 16B, sequential per row
    }
}

// ---------------- gate/up GEMM (bf16 weights, async staging) ----------------
__global__ __launch_bounds__(256) void gateup_k(
    const u16* __restrict__ xsc, const u16* __restrict__ xbf,
    const u16* __restrict__ wt,
    const int* __restrict__ counts, const int* __restrict__ offs,
    u16* __restrict__ Hbf, u16* __restrict__ Hs)
{
    int bid = blockIdx.x;
    int g  = bid >> 8;
    int mt = (bid >> 4) & 15;
    int nt = bid & 15;

    int M; const u16* A; const u16* Wg; const u16* Wu; u16* Ho;
    if (g < NE) {
        M = counts[g];
        int ro = offs[g];
        A  = xsc + (size_t)ro * DIM;
        Wg = wt + (size_t)g * MATSZ;
        Wu = wt + (size_t)(8 + g) * MATSZ;
        Ho = Hbf + (size_t)ro * FDIM;
    } else {
        M = T_TOK; A = xbf;
        Wg = wt + 24 * MATSZ;
        Wu = wt + 25 * MATSZ;
        Ho = Hs;
    }
    int m0 = mt * BM;
    if (m0 >= M) return;
    int n0 = nt * BN;

    __shared__ __align__(128) u16 As[BM * BK];
    __shared__ __align__(128) u16 Bg[BN * BK];
    __shared__ __align__(128) u16 Bu[BN * BK];

    int tid  = threadIdx.x;
    int lane = tid & 63;
    int w    = tid >> 6;
    int wm = (w >> 1) * 64;
    int wn = (w & 1) * 64;

    f32x4 accg[4][4], accu[4][4];
    #pragma unroll
    for (int i = 0; i < 4; ++i)
        #pragma unroll
        for (int j = 0; j < 4; ++j) { accg[i][j] = (f32x4)0.f; accu[i][j] = (f32x4)0.f; }

    // staging: wave w covers rows [w*16, w*16+16) and [64+w*16, ...); lane -> (row, 16B chunk)
    int r0 = w * 16 + (lane >> 2);
    int co = (lane & 3) * 8;
    const u16* gA0  = A  + (size_t)min(m0 + r0,      M - 1) * DIM + co;
    const u16* gA1  = A  + (size_t)min(m0 + 64 + r0, M - 1) * DIM + co;
    const u16* gBg0 = Wg + (size_t)(n0 + r0)      * DIM + co;
    const u16* gBg1 = Wg + (size_t)(n0 + 64 + r0) * DIM + co;
    const u16* gBu0 = Wu + (size_t)(n0 + r0)      * DIM + co;
    const u16* gBu1 = Wu + (size_t)(n0 + 64 + r0) * DIM + co;
    u16* lA0  = As + (w * 16) * BK;        // wave-uniform LDS bases
    u16* lA1  = As + (64 + w * 16) * BK;
    u16* lBg0 = Bg + (w * 16) * BK;
    u16* lBg1 = Bg + (64 + w * 16) * BK;
    u16* lBu0 = Bu + (w * 16) * BK;
    u16* lBu1 = Bu + (64 + w * 16) * BK;

    int am   = wm + (lane & 15);
    int koff = (lane >> 4) * 8;

    for (int k0 = 0; k0 < DIM; k0 += BK) {
        gload_lds16(gA0,  lA0);  gload_lds16(gA1,  lA1);
        gload_lds16(gBg0, lBg0); gload_lds16(gBg1, lBg1);
        gload_lds16(gBu0, lBu0); gload_lds16(gBu1, lBu1);
        gA0 += BK; gA1 += BK; gBg0 += BK; gBg1 += BK; gBu0 += BK; gBu1 += BK;
        __syncthreads();

        s16x8 af[4];
        #pragma unroll
        for (int i = 0; i < 4; ++i)
            af[i] = *(const s16x8*)&As[(am + i * 16) * BK + koff];
        #pragma unroll
        for (int j = 0; j < 4; ++j) {
            int bc = wn + j * 16 + (lane & 15);
            s16x8 bg = *(const s16x8*)&Bg[bc * BK + koff];
            s16x8 bu = *(const s16x8*)&Bu[bc * BK + koff];
            #pragma unroll
            for (int i = 0; i < 4; ++i) {
                accg[i][j] = __builtin_amdgcn_mfma_f32_16x16x32_bf16(af[i], bg, accg[i][j], 0, 0, 0);
                accu[i][j] = __builtin_amdgcn_mfma_f32_16x16x32_bf16(af[i], bu, accu[i][j], 0, 0, 0);
            }
        }
        __syncthreads();
    }

    int rbase = wm + ((lane >> 4) << 2);
    int cbase = n0 + wn + (lane & 15);
    #pragma unroll
    for (int i = 0; i < 4; ++i) {
        #pragma unroll
        for (int j = 0; j < 4; ++j) {
            #pragma unroll
            for (int r = 0; r < 4; ++r) {
                int row = m0 + rbase + i * 16 + r;
                if (row < M) {
                    float gv = accg[i][j][r];
                    float uv = accu[i][j][r];
                    float h = gv / (1.f + expf(-gv)) * uv;
                    Ho[(size_t)row * FDIM + cbase + j * 16] = f2bf(h);
                }
            }
        }
    }
}

// ---------------- down GEMM: experts -> out (unique writes), shared -> tmpS ----------------
__global__ __launch_bounds__(256) void down_k(
    const u16* __restrict__ Hbf, const u16* __restrict__ Hs,
    const u16* __restrict__ wt,
    const int* __restrict__ counts, const int* __restrict__ offs,
    const int* __restrict__ tokmap, float* __restrict__ out, float* __restrict__ tmpS)
{
    int bid = blockIdx.x;
    int g  = bid >> 8;
    int mt = (bid >> 4) & 15;
    int nt = bid & 15;

    int M, ro; const u16* A; const u16* W;
    if (g < NE) {
        M = counts[g];
        ro = offs[g];
        A = Hbf + (size_t)ro * FDIM;
        W = wt + (size_t)(16 + g) * MATSZ;
    } else {
        M = T_TOK; ro = 0; A = Hs; W = wt + 26 * MATSZ;
    }
    int m0 = mt * BM;
    if (m0 >= M) return;
    int n0 = nt * BN;

    __shared__ __align__(128) u16 As[BM * BK];
    __shared__ __align__(128) u16 Bd[BN * BK];

    int tid  = threadIdx.x;
    int lane = tid & 63;
    int w    = tid >> 6;
    int wm = (w >> 1) * 64;
    int wn = (w & 1) * 64;

    f32x4 acc[4][4];
    #pragma unroll
    for (int i = 0; i < 4; ++i)
        #pragma unroll
        for (int j = 0; j < 4; ++j) acc[i][j] = (f32x4)0.f;

    int r0 = w * 16 + (lane >> 2);
    int co = (lane & 3) * 8;
    const u16* gA0 = A + (size_t)min(m0 + r0,      M - 1) * FDIM + co;
    const u16* gA1 = A + (size_t)min(m0 + 64 + r0, M - 1) * FDIM + co;
    const u16* gB0 = W + (size_t)(n0 + r0)      * FDIM + co;
    const u16* gB1 = W + (size_t)(n0 + 64 + r0) * FDIM + co;
    u16* lA0 = As + (w * 16) * BK;
    u16* lA1 = As + (64 + w * 16) * BK;
    u16* lB0 = Bd + (w * 16) * BK;
    u16* lB1 = Bd + (64 + w * 16) * BK;

    int am   = wm + (lane & 15);
    int koff = (lane >> 4) * 8;

    for (int k0 = 0; k0 < FDIM; k0 += BK) {
        gload_lds16(gA0, lA0); gload_lds16(gA1, lA1);
        gload_lds16(gB0, lB0); gload_lds16(gB1, lB1);
        gA0 += BK; gA1 += BK; gB0 += BK; gB1 += BK;
        __syncthreads();

        s16x8 af[4];
        #pragma unroll
        for (int i = 0; i < 4; ++i)
            af[i] = *(const s16x8*)&As[(am + i * 16) * BK + koff];
        #pragma unroll
        for (int j = 0; j < 4; ++j) {
            int bc = wn + j * 16 + (lane & 15);
            s16x8 bd = *(const s16x8*)&Bd[bc * BK + koff];
            #pragma unroll
            for (int i = 0; i < 4; ++i)
                acc[i][j] = __builtin_amdgcn_mfma_f32_16x16x32_bf16(af[i], bd, acc[i][j], 0, 0, 0);
        }
        __syncthreads();
    }

    int rbase = wm + ((lane >> 4) << 2);
    int cbase = n0 + wn + (lane & 15);
    #pragma unroll
    for (int i = 0; i < 4; ++i) {
        #pragma unroll
        for (int r = 0; r < 4; ++r) {
            int row = m0 + rbase + i * 16 + r;
            if (row < M) {
                float* dst;
                if (g < NE) dst = out + (size_t)tokmap[ro + row] * DIM;
                else        dst = tmpS + (size_t)row * DIM;
                #pragma unroll
                for (int j = 0; j < 4; ++j)
                    dst[cbase + j * 16] = acc[i][j][r];
            }
        }
    }
}

__global__ __launch_bounds__(256) void add_k(float* __restrict__ out,
                                             const float* __restrict__ tmpS)
{
    int i = blockIdx.x * 256 + threadIdx.x;
    float4 o = ((const float4*)out)[i];
    float4 t = ((const float4*)tmpS)[i];
    o.x += t.x; o.y += t.y; o.z += t.z; o.w += t.w;
    ((float4*)out)[i] = o;
}

// ======================= fallback path (round-1, known-good) =======================
__device__ __forceinline__ void stageB_fb(const float* __restrict__ W, u16* Bs,
                                          int bn, int bkh)
{
    const float* wp = W + (size_t)bkh * FDIM + bn;
    alignas(16) u16 tmp[16];
    #pragma unroll
    for (int j = 0; j < 16; ++j) tmp[j] = f2bf(wp[(size_t)j * FDIM]);
    *(s16x8*)&Bs[bn * LDB + bkh]     = *(s16x8*)&tmp[0];
    *(s16x8*)&Bs[bn * LDB + bkh + 8] = *(s16x8*)&tmp[8];
}

__global__ __launch_bounds__(256) void gateup_fb(
    const u16* __restrict__ xsc, const u16* __restrict__ xbf,
    const float* __restrict__ gate_w, const float* __restrict__ up_w,
    const float* __restrict__ sgw, const float* __restrict__ suw,
    const int* __restrict__ counts, const int* __restrict__ offs,
    u16* __restrict__ Hbf, u16* __restrict__ Hs)
{
    int bid = blockIdx.x;
    int g  = bid >> 8;
    int mt = (bid >> 4) & 15;
    int nt = bid & 15;
    int M; const u16* A; const float* Wg; const float* Wu; u16* Ho;
    if (g < NE) {
        M = counts[g];
        int ro = offs[g];
        A  = xsc + (size_t)ro * DIM;
        Wg = gate_w + (size_t)g * DIM * FDIM;
        Wu = up_w  + (size_t)g * DIM * FDIM;
        Ho = Hbf + (size_t)ro * FDIM;
    } else {
        M = T_TOK; A = xbf; Wg = sgw; Wu = suw; Ho = Hs;
    }
    int m0 = mt * BM;
    if (m0 >= M) return;
    int n0 = nt * BN;
    __shared__ u16 As[BM * BK];
    __shared__ u16 Bg[BN * LDB];
    __shared__ u16 Bu[BN * LDB];
    int tid  = threadIdx.x;
    int lane = tid & 63;
    int wave = tid >> 6;
    int wm = (wave >> 1) * 64;
    int wn = (wave & 1) * 64;
    f32x4 accg[4][4], accu[4][4];
    #pragma unroll
    for (int i = 0; i < 4; ++i)
        #pragma unroll
        for (int j = 0; j < 4; ++j) { accg[i][j] = (f32x4)0.f; accu[i][j] = (f32x4)0.f; }
    int ar = tid >> 2;
    int ac = (tid & 3) * 8;
    int arow0 = min(m0 + ar,      M - 1);
    int arow1 = min(m0 + 64 + ar, M - 1);
    int bn  = tid & 127;
    int bkh = (tid >> 7) * 16;
    int am   = wm + (lane & 15);
    int koff = (lane >> 4) * 8;
    for (int k0 = 0; k0 < DIM; k0 += BK) {
        *(s16x8*)&As[ar * BK + ac]        = *(const s16x8*)&A[(size_t)arow0 * DIM + k0 + ac];
        *(s16x8*)&As[(64 + ar) * BK + ac] = *(const s16x8*)&A[(size_t)arow1 * DIM + k0 + ac];
        stageB_fb(Wg + (size_t)k0 * FDIM + n0, Bg, bn, bkh);
        stageB_fb(Wu + (size_t)k0 * FDIM + n0, Bu, bn, bkh);
        __syncthreads();
        s16x8 af[4];
        #pragma unroll
        for (int i = 0; i < 4; ++i)
            af[i] = *(const s16x8*)&As[(am + i * 16) * BK + koff];
        #pragma unroll
        for (int j = 0; j < 4; ++j) {
            int bc = wn + j * 16 + (lane & 15);
            s16x8 bg = *(const s16x8*)&Bg[bc * LDB + koff];
            s16x8 bu = *(const s16x8*)&Bu[bc * LDB + koff];
            #pragma unroll
            for (int i = 0; i < 4; ++i) {
                accg[i][j] = __builtin_amdgcn_mfma_f32_16x16x32_bf16(af[i], bg, accg[i][j], 0, 0, 0);
                accu[i][j] = __builtin_amdgcn_mfma_f32_16x16x32_bf16(af[i], bu, accu[i][j], 0, 0, 0);
            }
        }
        __syncthreads();
    }
    int rbase = wm + ((lane >> 4) << 2);
    int cbase = n0 + wn + (lane & 15);
    #pragma unroll
    for (int i = 0; i < 4; ++i) {
        #pragma unroll
        for (int j = 0; j < 4; ++j) {
            #pragma unroll
            for (int r = 0; r < 4; ++r) {
                int row = m0 + rbase + i * 16 + r;
                if (row < M) {
                    float gv = accg[i][j][r];
                    float uv = accu[i][j][r];
                    float h = gv / (1.f + expf(-gv)) * uv;
                    Ho[(size_t)row * FDIM + cbase + j * 16] = f2bf(h);
                }
            }
        }
    }
}

__global__ __launch_bounds__(256) void down_fb(
    const u16* __restrict__ Hbf, const u16* __restrict__ Hs,
    const float* __restrict__ down_w, const float* __restrict__ sdw,
    const int* __restrict__ counts, const int* __restrict__ offs,
    const int* __restrict__ tokmap, float* __restrict__ out)
{
    int bid = blockIdx.x;
    int g  = bid >> 8;
    int mt = (bid >> 4) & 15;
    int nt = bid & 15;
    int M, ro; const u16* A; const float* W;
    if (g < NE) {
        M = counts[g];
        ro = offs[g];
        A = Hbf + (size_t)ro * FDIM;
        W = down_w + (size_t)g * FDIM * DIM;
    } else {
        M = T_TOK; ro = 0; A = Hs; W = sdw;
    }
    int m0 = mt * BM;
    if (m0 >= M) return;
    int n0 = nt * BN;
    __shared__ u16 As[BM * BK];
    __shared__ u16 Bd[BN * LDB];
    int tid  = threadIdx.x;
    int lane = tid & 63;
    int wave = tid >> 6;
    int wm = (wave >> 1) * 64;
    int wn = (wave & 1) * 64;
    f32x4 acc[4][4];
    #pragma unroll
    for (int i = 0; i < 4; ++i)
        #pragma unroll
        for (int j = 0; j < 4; ++j) acc[i][j] = (f32x4)0.f;
    int ar = tid >> 2;
    int ac = (tid & 3) * 8;
    int arow0 = min(m0 + ar,      M - 1);
    int arow1 = min(m0 + 64 + ar, M - 1);
    int bn  = tid & 127;
    int bkh = (tid >> 7) * 16;
    int am   = wm + (lane & 15);
    int koff = (lane >> 4) * 8;
    for (int k0 = 0; k0 < FDIM; k0 += BK) {
        *(s16x8*)&As[ar * BK + ac]        = *(const s16x8*)&A[(size_t)arow0 * FDIM + k0 + ac];
        *(s16x8*)&As[(64 + ar) * BK + ac] = *(const s16x8*)&A[(size_t)arow1 * FDIM + k0 + ac];
        stageB_fb(W + (size_t)k0 * DIM + n0, Bd, bn, bkh);
        __syncthreads();
        s16x8 af[4];
        #pragma unroll
        for (int i = 0; i < 4; ++i)
            af[i] = *(const s16x8*)&As[(am + i * 16) * BK + koff];
        #pragma unroll
        for (int j = 0; j < 4; ++j) {
            int bc = wn + j * 16 + (lane & 15);
            s16x8 bd = *(const s16x8*)&Bd[bc * LDB + koff];
            #pragma unroll
            for (int i = 0; i < 4; ++i)
                acc[i][j] = __builtin_amdgcn_mfma_f32_16x16x32_bf16(af[i], bd, acc[i][j], 0, 0, 0);
        }
        __syncthreads();
    }
    int rbase = wm + ((lane >> 4) << 2);
    int cbase = n0 + wn + (lane & 15);
    #pragma unroll
    for (int i = 0; i < 4; ++i) {
        #pragma unroll
        for (int r = 0; r < 4; ++r) {
            int row = m0 + rbase + i * 16 + r;
            if (row < M) {
                int tok = (g < NE) ? tokmap[ro + row] : row;
                #pragma unroll
                for (int j = 0; j < 4; ++j)
                    atomicAdd(&out[(size_t)tok * DIM + cbase + j * 16], acc[i][j][r]);
            }
        }
    }
}

// ======================= host =======================
extern "C" void kernel_launch(void* const* d_in, const int* in_sizes, int n_in,
                              void* d_out, int out_size, void* d_ws, size_t ws_size,
                              hipStream_t stream) {
    const float* x   = (const float*)d_in[0];
    const float* rw  = (const float*)d_in[1];
    const float* gw  = (const float*)d_in[2];
    const float* uw  = (const float*)d_in[3];
    const float* dwn = (const float*)d_in[4];
    const float* sgw = (const float*)d_in[5];
    const float* suw = (const float*)d_in[6];
    const float* sdw = (const float*)d_in[7];
    float* out = (float*)d_out;

    char* ws = (char*)d_ws;
    float* score = (float*)(ws);
    int* eidx    = (int*)(ws + 8192);
    int* counts  = (int*)(ws + 16384);
    int* fill    = (int*)(ws + 16448);
    int* offs    = (int*)(ws + 16512);
    int* tokmap  = (int*)(ws + 16576);
    u16* xsc = (u16*)(ws + 32768);
    u16* xbf = xsc + MATSZ;
    u16* Hbf = xbf + MATSZ;
    u16* Hs  = Hbf + MATSZ;
    float* tmpS = (float*)(ws + 32768 + 4ull * 8388608);
    u16* wt = (u16*)(ws + 32768 + 4ull * 8388608 + 16777216);
    const size_t WS_NEED = 32768 + 4ull * 8388608 + 16777216 + 27ull * 8388608;
    bool big = ws_size >= WS_NEED;

    hipMemsetAsync(counts, 0, 128, stream);   // counts + fill
    router_k<<<T_TOK, 256, 0, stream>>>(x, rw, score, eidx, counts);
    scan_k<<<1, 64, 0, stream>>>(counts, offs, fill);
    gather_k<<<T_TOK, 256, 0, stream>>>(x, score, eidx, fill, tokmap, xsc, xbf);

    if (big) {
        wtrans_k<<<27 * 32, 256, 0, stream>>>(gw, uw, dwn, sgw, suw, sdw, wt);
        gateup_k<<<NE * 256 + 256, 256, 0, stream>>>(xsc, xbf, wt, counts, offs, Hbf, Hs);
        down_k<<<NE * 256 + 256, 256, 0, stream>>>(Hbf, Hs, wt, counts, offs, tokmap, out, tmpS);
        add_k<<<(T_TOK * DIM) / (256 * 4), 256, 0, stream>>>(out, tmpS);
    } else {
        hipMemsetAsync(out, 0, (size_t)out_size * sizeof(float), stream);
        gateup_fb<<<NE * 256 + 256, 256, 0, stream>>>(xsc, xbf, gw, uw, sgw, suw,
                                                      counts, offs, Hbf, Hs);
        down_fb<<<NE * 256 + 256, 256, 0, stream>>>(Hbf, Hs, dwn, sdw,
                                                    counts, offs, tokmap, out);
    }
}

// Round 3
// 730.378 us; speedup vs baseline: 1.3435x; 1.3435x over previous
//
#include <hip/hip_runtime.h>
#include <stdint.h>
#include <math.h>

#define T_TOK 2048
#define DIM   2048
#define FDIM  2048
#define NE    8

#define BM 64
#define BN 128
#define BK 32
#define MATSZ 4194304ull  // 2048*2048

// wt matrix index map: 0..7 gate, 8..15 up, 16 shared_gate, 17 shared_up,
//                      18..25 down, 26 shared_down
typedef unsigned short u16;
typedef short s16x8 __attribute__((ext_vector_type(8)));
typedef float f32x4 __attribute__((ext_vector_type(4)));

__device__ __forceinline__ u16 f2bf(float f) {
    union { float f; unsigned int u; } v; v.f = f;
    unsigned int r = v.u + 0x7FFFu + ((v.u >> 16) & 1u);  // RNE
    return (u16)(r >> 16);
}

// async 16B global -> LDS. lds ptr wave-uniform; HW deposits at base + lane*16.
__device__ __forceinline__ void gload_lds16(const void* g, void* l) {
    __builtin_amdgcn_global_load_lds((const __attribute__((address_space(1))) void*)g,
                                     (__attribute__((address_space(3))) void*)l, 16, 0, 0);
}

// ---------------- router ----------------
__global__ __launch_bounds__(256) void router_k(
    const float* __restrict__ x, const float* __restrict__ rw,
    float* __restrict__ score, int* __restrict__ eidx, int* __restrict__ counts)
{
    int t = blockIdx.x;
    int tid = threadIdx.x;
    float p[8] = {0.f,0.f,0.f,0.f,0.f,0.f,0.f,0.f};
    const float* xrow = x + (size_t)t * DIM;
    for (int d = tid; d < DIM; d += 256) {
        float xv = xrow[d];
        const float4* r = (const float4*)(rw + (size_t)d * 8);
        float4 r0 = r[0], r1 = r[1];
        p[0] += xv * r0.x; p[1] += xv * r0.y; p[2] += xv * r0.z; p[3] += xv * r0.w;
        p[4] += xv * r1.x; p[5] += xv * r1.y; p[6] += xv * r1.z; p[7] += xv * r1.w;
    }
    #pragma unroll
    for (int off = 32; off > 0; off >>= 1) {
        #pragma unroll
        for (int e = 0; e < 8; ++e) p[e] += __shfl_down(p[e], off);
    }
    __shared__ float red[4][8];
    int wave = tid >> 6, lane = tid & 63;
    if (lane == 0) {
        #pragma unroll
        for (int e = 0; e < 8; ++e) red[wave][e] = p[e];
    }
    __syncthreads();
    if (tid == 0) {
        float lg[8];
        #pragma unroll
        for (int e = 0; e < 8; ++e) lg[e] = red[0][e] + red[1][e] + red[2][e] + red[3][e];
        int best = 0; float bv = lg[0];
        #pragma unroll
        for (int e = 1; e < 8; ++e) { if (lg[e] > bv) { bv = lg[e]; best = e; } }
        score[t] = 1.f / (1.f + expf(-bv));
        eidx[t] = best;
        atomicAdd(&counts[best], 1);
    }
}

__global__ void scan_k(const int* __restrict__ counts, int* __restrict__ offs,
                       int* __restrict__ fill)
{
    if (threadIdx.x == 0 && blockIdx.x == 0) {
        int run = 0;
        for (int e = 0; e < NE; ++e) { offs[e] = run; fill[e] = run; run += counts[e]; }
    }
}

// ---------------- gather ----------------
__global__ __launch_bounds__(256) void gather_k(
    const float* __restrict__ x, const float* __restrict__ score,
    const int* __restrict__ eidx, int* __restrict__ fill,
    int* __restrict__ tokmap, u16* __restrict__ xsc, u16* __restrict__ xbf)
{
    int t = blockIdx.x, tid = threadIdx.x;
    __shared__ int sp;
    if (tid == 0) {
        int e = eidx[t];
        int p = atomicAdd(&fill[e], 1);
        tokmap[p] = t;
        sp = p;
    }
    __syncthreads();
    int pos = sp;
    float s = score[t];
    const float4* xr = (const float4*)(x + (size_t)t * DIM);
    float4 a = xr[tid * 2], b = xr[tid * 2 + 1];
    alignas(16) u16 raw[8] = { f2bf(a.x), f2bf(a.y), f2bf(a.z), f2bf(a.w),
                               f2bf(b.x), f2bf(b.y), f2bf(b.z), f2bf(b.w) };
    alignas(16) u16 scl[8] = { f2bf(a.x*s), f2bf(a.y*s), f2bf(a.z*s), f2bf(a.w*s),
                               f2bf(b.x*s), f2bf(b.y*s), f2bf(b.z*s), f2bf(b.w*s) };
    *(s16x8*)(xbf + (size_t)t * DIM + tid * 8)   = *(s16x8*)raw;
    *(s16x8*)(xsc + (size_t)pos * DIM + tid * 8) = *(s16x8*)scl;
}

// ---------------- weight transpose: fp32 [K][N] -> bf16 [N][K], LDS-tiled ----------------
// 64(k) x 256(n) tile per block; coalesced reads AND writes.
#define TLDS 260   // padded n-stride in u16 (8B-aligned rows, odd dword count)
__global__ __launch_bounds__(256) void wtrans_k(
    const float* __restrict__ gw, const float* __restrict__ uw,
    const float* __restrict__ dwn, const float* __restrict__ sgw,
    const float* __restrict__ suw, const float* __restrict__ sdw,
    u16* __restrict__ wt, int mstart)
{
    int bid = blockIdx.x;
    int m = mstart + (bid >> 8);      // 256 blocks per matrix: 32 kt x 8 nt
    int kt = (bid >> 3) & 31;
    int nt = bid & 7;
    const float* src;
    if      (m < 8)   src = gw  + (size_t)m * MATSZ;
    else if (m < 16)  src = uw  + (size_t)(m - 8) * MATSZ;
    else if (m == 16) src = sgw;
    else if (m == 17) src = suw;
    else if (m < 26)  src = dwn + (size_t)(m - 18) * MATSZ;
    else              src = sdw;
    u16* dst = wt + (size_t)m * MATSZ;

    int k0 = kt * 64, n0 = nt * 256;
    __shared__ u16 T[64 * TLDS];
    int t = threadIdx.x;
    int lw = t >> 6, l = t & 63;

    // read phase: wave lw covers k rows [lw*16, lw*16+16); lane reads float4 along n
    #pragma unroll 4
    for (int i = 0; i < 16; ++i) {
        int kk = lw * 16 + i;
        float4 v = *(const float4*)&src[(size_t)(k0 + kk) * 2048 + n0 + l * 4];
        alignas(8) u16 b4[4] = { f2bf(v.x), f2bf(v.y), f2bf(v.z), f2bf(v.w) };
        *(uint64_t*)&T[kk * TLDS + l * 4] = *(uint64_t*)b4;
    }
    __syncthreads();

    // write phase: thread -> (n row, 16B k-chunk); rotated j-order breaks bank aliasing
    int c  = t & 7;        // k chunk
    int nb = t >> 3;       // n within pass
    #pragma unroll
    for (int p = 0; p < 8; ++p) {
        int n = p * 32 + nb;
        alignas(16) u16 o[8];
        #pragma unroll
        for (int jj = 0; jj < 8; ++jj) {
            int j = (jj + c) & 7;
            o[j] = T[(c * 8 + j) * TLDS + n];
        }
        *(s16x8*)&dst[(size_t)(n0 + n) * 2048 + k0 + c * 8] = *(s16x8*)o;
    }
}

// ---------------- gate/up GEMM (BM=64): H = silu(X Wg) * (X Wu) -> bf16 ----------------
__global__ __launch_bounds__(256) void gateup_k(
    const u16* __restrict__ xsc, const u16* __restrict__ xbf,
    const u16* __restrict__ wt,
    const int* __restrict__ counts, const int* __restrict__ offs,
    u16* __restrict__ Hbf, u16* __restrict__ Hs)
{
    int bid = blockIdx.x;
    int g  = bid >> 9;
    int mt = (bid >> 4) & 31;
    int nt = bid & 15;

    int M; const u16* A; const u16* Wg; const u16* Wu; u16* Ho;
    if (g < NE) {
        M = counts[g];
        int ro = offs[g];
        A  = xsc + (size_t)ro * DIM;
        Wg = wt + (size_t)g * MATSZ;
        Wu = wt + (size_t)(8 + g) * MATSZ;
        Ho = Hbf + (size_t)ro * FDIM;
    } else {
        M = T_TOK; A = xbf;
        Wg = wt + 16 * MATSZ;
        Wu = wt + 17 * MATSZ;
        Ho = Hs;
    }
    int m0 = mt * BM;
    if (m0 >= M) return;
    int n0 = nt * BN;

    __shared__ __align__(128) u16 As[BM * BK];
    __shared__ __align__(128) u16 Bg[BN * BK];
    __shared__ __align__(128) u16 Bu[BN * BK];

    int tid = threadIdx.x;
    int l   = tid & 63;
    int w   = tid >> 6;
    int wm = (w >> 1) * 32;
    int wn = (w & 1) * 64;

    f32x4 accg[2][4], accu[2][4];
    #pragma unroll
    for (int i = 0; i < 2; ++i)
        #pragma unroll
        for (int j = 0; j < 4; ++j) { accg[i][j] = (f32x4)0.f; accu[i][j] = (f32x4)0.f; }

    int rr = l >> 2;
    int co = (l & 3) * 8;
    const u16* gA   = A  + (size_t)min(m0 + w * 16 + rr, M - 1) * DIM + co;
    const u16* gBg0 = Wg + (size_t)(n0 + w * 16 + rr)      * DIM + co;
    const u16* gBg1 = Wg + (size_t)(n0 + 64 + w * 16 + rr) * DIM + co;
    const u16* gBu0 = Wu + (size_t)(n0 + w * 16 + rr)      * DIM + co;
    const u16* gBu1 = Wu + (size_t)(n0 + 64 + w * 16 + rr) * DIM + co;
    u16* lA   = As + (w * 16) * BK;
    u16* lBg0 = Bg + (w * 16) * BK;
    u16* lBg1 = Bg + (64 + w * 16) * BK;
    u16* lBu0 = Bu + (w * 16) * BK;
    u16* lBu1 = Bu + (64 + w * 16) * BK;

    int am   = wm + (l & 15);
    int koff = (l >> 4) * 8;

    for (int k0 = 0; k0 < DIM; k0 += BK) {
        gload_lds16(gA,   lA);
        gload_lds16(gBg0, lBg0); gload_lds16(gBg1, lBg1);
        gload_lds16(gBu0, lBu0); gload_lds16(gBu1, lBu1);
        gA += BK; gBg0 += BK; gBg1 += BK; gBu0 += BK; gBu1 += BK;
        __syncthreads();

        s16x8 af0 = *(const s16x8*)&As[am * BK + koff];
        s16x8 af1 = *(const s16x8*)&As[(am + 16) * BK + koff];
        #pragma unroll
        for (int j = 0; j < 4; ++j) {
            int bc = wn + j * 16 + (l & 15);
            s16x8 bg = *(const s16x8*)&Bg[bc * BK + koff];
            s16x8 bu = *(const s16x8*)&Bu[bc * BK + koff];
            accg[0][j] = __builtin_amdgcn_mfma_f32_16x16x32_bf16(af0, bg, accg[0][j], 0, 0, 0);
            accg[1][j] = __builtin_amdgcn_mfma_f32_16x16x32_bf16(af1, bg, accg[1][j], 0, 0, 0);
            accu[0][j] = __builtin_amdgcn_mfma_f32_16x16x32_bf16(af0, bu, accu[0][j], 0, 0, 0);
            accu[1][j] = __builtin_amdgcn_mfma_f32_16x16x32_bf16(af1, bu, accu[1][j], 0, 0, 0);
        }
        __syncthreads();
    }

    int rbase = wm + ((l >> 4) << 2);
    int cbase = n0 + wn + (l & 15);
    #pragma unroll
    for (int i = 0; i < 2; ++i) {
        #pragma unroll
        for (int j = 0; j < 4; ++j) {
            #pragma unroll
            for (int r = 0; r < 4; ++r) {
                int row = m0 + rbase + i * 16 + r;
                if (row < M) {
                    float gv = accg[i][j][r];
                    float uv = accu[i][j][r];
                    float h = gv / (1.f + expf(-gv)) * uv;
                    Ho[(size_t)row * FDIM + cbase + j * 16] = f2bf(h);
                }
            }
        }
    }
}

// ---------------- down GEMM (BM=64): shared pass stores out; expert pass RMWs ----------------
__global__ __launch_bounds__(256) void down_k(
    const u16* __restrict__ Hbf, const u16* __restrict__ Hs,
    const u16* __restrict__ wt,
    const int* __restrict__ counts, const int* __restrict__ offs,
    const int* __restrict__ tokmap, float* __restrict__ out, int shared_pass)
{
    int bid = blockIdx.x;
    int g, mt, nt, M, ro; const u16* A; const u16* W;
    if (shared_pass) {
        g = NE; mt = bid >> 4; nt = bid & 15;
        M = T_TOK; ro = 0; A = Hs; W = wt + 26 * MATSZ;
    } else {
        g = bid >> 9; mt = (bid >> 4) & 31; nt = bid & 15;
        M = counts[g]; ro = offs[g];
        A = Hbf + (size_t)ro * FDIM;
        W = wt + (size_t)(18 + g) * MATSZ;
    }
    int m0 = mt * BM;
    if (m0 >= M) return;
    int n0 = nt * BN;

    __shared__ __align__(128) u16 As[BM * BK];
    __shared__ __align__(128) u16 Bd[BN * BK];

    int tid = threadIdx.x;
    int l   = tid & 63;
    int w   = tid >> 6;
    int wm = (w >> 1) * 32;
    int wn = (w & 1) * 64;

    f32x4 acc[2][4];
    #pragma unroll
    for (int i = 0; i < 2; ++i)
        #pragma unroll
        for (int j = 0; j < 4; ++j) acc[i][j] = (f32x4)0.f;

    int rr = l >> 2;
    int co = (l & 3) * 8;
    const u16* gA  = A + (size_t)min(m0 + w * 16 + rr, M - 1) * FDIM + co;
    const u16* gB0 = W + (size_t)(n0 + w * 16 + rr)      * FDIM + co;
    const u16* gB1 = W + (size_t)(n0 + 64 + w * 16 + rr) * FDIM + co;
    u16* lA  = As + (w * 16) * BK;
    u16* lB0 = Bd + (w * 16) * BK;
    u16* lB1 = Bd + (64 + w * 16) * BK;

    int am   = wm + (l & 15);
    int koff = (l >> 4) * 8;

    for (int k0 = 0; k0 < FDIM; k0 += BK) {
        gload_lds16(gA, lA);
        gload_lds16(gB0, lB0); gload_lds16(gB1, lB1);
        gA += BK; gB0 += BK; gB1 += BK;
        __syncthreads();

        s16x8 af0 = *(const s16x8*)&As[am * BK + koff];
        s16x8 af1 = *(const s16x8*)&As[(am + 16) * BK + koff];
        #pragma unroll
        for (int j = 0; j < 4; ++j) {
            int bc = wn + j * 16 + (l & 15);
            s16x8 bd = *(const s16x8*)&Bd[bc * BK + koff];
            acc[0][j] = __builtin_amdgcn_mfma_f32_16x16x32_bf16(af0, bd, acc[0][j], 0, 0, 0);
            acc[1][j] = __builtin_amdgcn_mfma_f32_16x16x32_bf16(af1, bd, acc[1][j], 0, 0, 0);
        }
        __syncthreads();
    }

    int rbase = wm + ((l >> 4) << 2);
    int cbase = n0 + wn + (l & 15);
    #pragma unroll
    for (int i = 0; i < 2; ++i) {
        #pragma unroll
        for (int r = 0; r < 4; ++r) {
            int row = m0 + rbase + i * 16 + r;
            if (row < M) {
                if (shared_pass) {
                    float* dst = out + (size_t)row * DIM;
                    #pragma unroll
                    for (int j = 0; j < 4; ++j) dst[cbase + j * 16] = acc[i][j][r];
                } else {
                    // safe non-atomic RMW: (token,col) owned by exactly one expert block;
                    // shared pass completed (prior dispatch on same stream).
                    float* dst = out + (size_t)tokmap[ro + row] * DIM;
                    #pragma unroll
                    for (int j = 0; j < 4; ++j)
                        dst[cbase + j * 16] = dst[cbase + j * 16] + acc[i][j][r];
                }
            }
        }
    }
}

// ======================= host =======================
extern "C" void kernel_launch(void* const* d_in, const int* in_sizes, int n_in,
                              void* d_out, int out_size, void* d_ws, size_t ws_size,
                              hipStream_t stream) {
    const float* x   = (const float*)d_in[0];
    const float* rw  = (const float*)d_in[1];
    const float* gw  = (const float*)d_in[2];
    const float* uw  = (const float*)d_in[3];
    const float* dwn = (const float*)d_in[4];
    const float* sgw = (const float*)d_in[5];
    const float* suw = (const float*)d_in[6];
    const float* sdw = (const float*)d_in[7];
    float* out = (float*)d_out;

    char* ws = (char*)d_ws;
    float* score = (float*)(ws);
    int* eidx    = (int*)(ws + 8192);
    int* counts  = (int*)(ws + 16384);
    int* fill    = (int*)(ws + 16448);
    int* offs    = (int*)(ws + 16512);
    int* tokmap  = (int*)(ws + 16576);
    u16* xsc = (u16*)(ws + 32768);
    u16* xbf = xsc + MATSZ;
    u16* Hbf = xbf + MATSZ;
    u16* Hs  = Hbf + MATSZ;
    u16* wt  = (u16*)(ws + 32768 + 4ull * 8388608 + 16777216);

    hipMemsetAsync(counts, 0, 128, stream);   // counts + fill

    router_k<<<T_TOK, 256, 0, stream>>>(x, rw, score, eidx, counts);
    scan_k<<<1, 64, 0, stream>>>(counts, offs, fill);
    gather_k<<<T_TOK, 256, 0, stream>>>(x, score, eidx, fill, tokmap, xsc, xbf);

    // gate/up (+shared gate/up) weights -> bf16 [N][K], then gate/up GEMM (L3-warm)
    wtrans_k<<<18 * 256, 256, 0, stream>>>(gw, uw, dwn, sgw, suw, sdw, wt, 0);
    gateup_k<<<9 * 512, 256, 0, stream>>>(xsc, xbf, wt, counts, offs, Hbf, Hs);

    // down (+shared down) weights, then down GEMMs: shared stores, experts RMW
    wtrans_k<<<9 * 256, 256, 0, stream>>>(gw, uw, dwn, sgw, suw, sdw, wt, 18);
    down_k<<<512, 256, 0, stream>>>(Hbf, Hs, wt, counts, offs, tokmap, out, 1);
    down_k<<<8 * 512, 256, 0, stream>>>(Hbf, Hs, wt, counts, offs, tokmap, out, 0);
}